// Round 4
// baseline (738.924 us; speedup 1.0000x reference)
//
#include <hip/hip_runtime.h>
#include <math.h>

#define N_NODES 50000
#define N_EDGES 800000
#define D_FEAT 128
#define D_EDGE 64
#define HID 128
#define OUT_DIM 32

typedef unsigned short u16;
typedef short bf16x8 __attribute__((ext_vector_type(8)));
typedef float f32x4 __attribute__((ext_vector_type(4)));

__device__ __forceinline__ u16 f2bf(float x) {           // RNE fp32 -> bf16 bits
    unsigned u = __float_as_uint(x);
    unsigned r = (u >> 16) & 1u;
    return (u16)((u + 0x7FFFu + r) >> 16);
}
__device__ __forceinline__ float bf2f(u16 s) { return __uint_as_float(((unsigned)s) << 16); }
__device__ __forceinline__ float bflo(unsigned u) { return __uint_as_float(u << 16); }
__device__ __forceinline__ float bfhi(unsigned u) { return __uint_as_float(u & 0xFFFF0000u); }

// ---------------------------------------------------------------- utilities
__global__ void zero_i32(int* __restrict__ p, int n) {
    int i = blockIdx.x * 256 + threadIdx.x;
    if (i < n) p[i] = 0;
}

// ---- prep: transpose+cvt weights to bf16 once.
// WT_all[m][c][k] (m=0,1,2 -> Wq,Wk,Wv; 128x128), then WuT[c][k] (32x128)
// appended at offset 49152; WeTg[c][k] (128x64).
__global__ void prep_weights(const float* __restrict__ Wq, const float* __restrict__ Wk,
                             const float* __restrict__ Wv, const float* __restrict__ We,
                             const float* __restrict__ Wu,
                             u16* __restrict__ WT_all, u16* __restrict__ WeTg) {
    int id = blockIdx.x * 256 + threadIdx.x;   // 61440 threads
    if (id < 49152) {
        int m = id >> 14, rem = id & 16383;
        int c = rem >> 7, k = rem & 127;
        const float* W = (m == 0) ? Wq : (m == 1) ? Wk : Wv;
        WT_all[id] = f2bf(W[k * HID + c]);
    } else if (id < 57344) {
        int j = id - 49152;                    // 8192: WeTg
        int c = j >> 6, k = j & 63;
        WeTg[j] = f2bf(We[k * HID + c]);
    } else {
        int j = id - 57344;                    // 4096: WuT [32][128]
        int c = j >> 7, k = j & 127;
        WT_all[49152 + j] = f2bf(Wu[k * OUT_DIM + c]);
    }
}

// ------------------------------------------------- K1: Q/K/V/base GEMM via MFMA
// ONE block computes Q,K,V AND nodes@Wu+bu for 128 nodes (nodes read once).
// Wave-private LDS staging -> no __syncthreads.
// V stored HEAD-INTERLEAVED: Vp[n][d*4+h]. baseout is f32 [n][32].
__global__ __launch_bounds__(256) void node_qkv_v3(
    const float* __restrict__ nodes, const u16* __restrict__ WT_all,
    const float* __restrict__ bq, const float* __restrict__ bk, const float* __restrict__ bv,
    const float* __restrict__ bu,
    u16* __restrict__ Q, u16* __restrict__ Kk, u16* __restrict__ Vp,
    float* __restrict__ baseout)
{
    __shared__ __align__(16) u16 Alds[4][32 * 136];   // 34.8 KB, wave-private quadrants

    const int tid = threadIdx.x;
    const int wave = tid >> 6, lane = tid & 63;
    const int quad = lane >> 4, l15 = lane & 15;
    const int rowbase = blockIdx.x * 128 + wave * 32;

    u16* As = &Alds[wave][0];
    // wave-private staging: 32 rows x 128 cols, coalesced within wave
    #pragma unroll
    for (int it = 0; it < 16; ++it) {
        int idx = lane + it * 64;              // 1024 float4s per wave
        int row = idx >> 5, k4 = (idx & 31) * 4;
        float4 v = make_float4(0.f, 0.f, 0.f, 0.f);
        if (rowbase + row < N_NODES)
            v = *(const float4*)&nodes[(size_t)(rowbase + row) * D_FEAT + k4];
        ushort4 b;
        b.x = f2bf(v.x); b.y = f2bf(v.y); b.z = f2bf(v.z); b.w = f2bf(v.w);
        *(ushort4*)&As[row * 136 + k4] = b;
    }
    // no barrier: same-wave ds_write -> ds_read ordered by lgkmcnt

    bf16x8 afr[2][4];
    #pragma unroll
    for (int rt = 0; rt < 2; ++rt)
        #pragma unroll
        for (int ks = 0; ks < 4; ++ks)
            afr[rt][ks] = *(const bf16x8*)&As[(rt * 16 + l15) * 136 + ks * 32 + quad * 8];

    #pragma unroll
    for (int m = 0; m < 3; ++m) {
        const u16* WT = WT_all + (size_t)m * 16384;
        const float* bvec = (m == 0) ? bq : (m == 1) ? bk : bv;
        u16* C = (m == 0) ? Q : (m == 1) ? Kk : Vp;

        f32x4 acc[2][8];
        #pragma unroll
        for (int rt = 0; rt < 2; ++rt)
            #pragma unroll
            for (int ct = 0; ct < 8; ++ct)
                acc[rt][ct] = (f32x4){0.f, 0.f, 0.f, 0.f};

        #pragma unroll
        for (int ks = 0; ks < 4; ++ks) {
            #pragma unroll
            for (int ct = 0; ct < 8; ++ct) {
                bf16x8 b = *(const bf16x8*)&WT[(ct * 16 + l15) * 128 + ks * 32 + quad * 8];
                acc[0][ct] = __builtin_amdgcn_mfma_f32_16x16x32_bf16(afr[0][ks], b, acc[0][ct], 0, 0, 0);
                acc[1][ct] = __builtin_amdgcn_mfma_f32_16x16x32_bf16(afr[1][ks], b, acc[1][ct], 0, 0, 0);
            }
        }

        // epilogue: C layout row=quad*4+r (+rt*16), col=ct*16+l15
        #pragma unroll
        for (int ct = 0; ct < 8; ++ct) {
            int cbase = ct * 16 + l15;
            float bias = bvec[cbase];
            int oidx = (m == 2) ? ((cbase & 31) * 4 + (cbase >> 5)) : cbase;
            #pragma unroll
            for (int rt = 0; rt < 2; ++rt)
                #pragma unroll
                for (int r = 0; r < 4; ++r) {
                    int n = rowbase + rt * 16 + quad * 4 + r;
                    if (n < N_NODES)
                        C[(size_t)n * HID + oidx] = f2bf(acc[rt][ct][r] + bias);
                }
        }
    }

    // ---- base pass: nodes@Wu + bu -> baseout f32 (32 cols)
    {
        const u16* WuT = WT_all + 49152;
        f32x4 accu[2][2];
        #pragma unroll
        for (int rt = 0; rt < 2; ++rt)
            #pragma unroll
            for (int ct = 0; ct < 2; ++ct)
                accu[rt][ct] = (f32x4){0.f, 0.f, 0.f, 0.f};
        #pragma unroll
        for (int ks = 0; ks < 4; ++ks) {
            #pragma unroll
            for (int ct = 0; ct < 2; ++ct) {
                bf16x8 b = *(const bf16x8*)&WuT[(ct * 16 + l15) * 128 + ks * 32 + quad * 8];
                accu[0][ct] = __builtin_amdgcn_mfma_f32_16x16x32_bf16(afr[0][ks], b, accu[0][ct], 0, 0, 0);
                accu[1][ct] = __builtin_amdgcn_mfma_f32_16x16x32_bf16(afr[1][ks], b, accu[1][ct], 0, 0, 0);
            }
        }
        #pragma unroll
        for (int ct = 0; ct < 2; ++ct) {
            int cbase = ct * 16 + l15;
            float bias = bu[cbase];
            #pragma unroll
            for (int rt = 0; rt < 2; ++rt)
                #pragma unroll
                for (int r = 0; r < 4; ++r) {
                    int n = rowbase + rt * 16 + quad * 4 + r;
                    if (n < N_NODES)
                        baseout[(size_t)n * OUT_DIM + cbase] = accu[rt][ct][r] + bias;
                }
        }
    }
}

// ---------------------------------------------- CSR build
__global__ void hist_kernel(const int* __restrict__ receivers, int* __restrict__ count) {
    int e = blockIdx.x * 256 + threadIdx.x;
    atomicAdd(&count[receivers[e]], 1);
}

__global__ __launch_bounds__(256) void scan1(const int* __restrict__ count,
                                             int* __restrict__ incl, int* __restrict__ bsum) {
    __shared__ int sh[256];
    int gid = blockIdx.x * 256 + threadIdx.x;
    int v = (gid < N_NODES) ? count[gid] : 0;
    sh[threadIdx.x] = v; __syncthreads();
    #pragma unroll
    for (int off = 1; off < 256; off <<= 1) {
        int t = (threadIdx.x >= off) ? sh[threadIdx.x - off] : 0;
        __syncthreads();
        sh[threadIdx.x] += t;
        __syncthreads();
    }
    if (gid < N_NODES) incl[gid] = sh[threadIdx.x];
    if (threadIdx.x == 255) bsum[blockIdx.x] = sh[255];
}

__global__ __launch_bounds__(256) void scan2(const int* __restrict__ bsum,
                                             int* __restrict__ boff, int nblocks) {
    __shared__ int sh[256];
    int v = (threadIdx.x < nblocks) ? bsum[threadIdx.x] : 0;
    sh[threadIdx.x] = v; __syncthreads();
    #pragma unroll
    for (int off = 1; off < 256; off <<= 1) {
        int t = (threadIdx.x >= off) ? sh[threadIdx.x - off] : 0;
        __syncthreads();
        sh[threadIdx.x] += t;
        __syncthreads();
    }
    boff[threadIdx.x] = sh[threadIdx.x] - v;   // exclusive
}

__global__ __launch_bounds__(256) void scan3(const int* __restrict__ incl,
                                             const int* __restrict__ count,
                                             const int* __restrict__ boff,
                                             int* __restrict__ startp, int* __restrict__ cursor) {
    int gid = blockIdx.x * 256 + threadIdx.x;
    if (gid < N_NODES) {
        int ex = incl[gid] - count[gid] + boff[blockIdx.x];
        startp[gid] = ex;
        cursor[gid] = ex;
    }
    if (gid == 0) startp[N_NODES] = N_EDGES;
}

// v4: write ONLY sorted (1 scattered array, not 3). s/r re-derived in logits
// via 4B gathers from the 3.2MB L2-resident senders/receivers arrays.
__global__ void scatter_v4(const int* __restrict__ receivers,
                           int* __restrict__ cursor, int* __restrict__ sorted) {
    int e = blockIdx.x * 256 + threadIdx.x;
    int r = receivers[e];
    int pos = atomicAdd(&cursor[r], 1);
    sorted[pos] = e;
}

// ------------- K3 v5: logits in CSR slot order (Q rows L1-hot), but:
//  - wexp written scattered to ORIGINAL edge order (messages reads coalesced)
//  - denominator accumulated via f32 atomics into denomv[n][4] (800KB, L2)
// This deletes the whole denom/normalize pass.
__global__ __launch_bounds__(256) void edge_logits_v5(
    const u16* __restrict__ Q, const u16* __restrict__ K,
    const int* __restrict__ sorted, const int* __restrict__ senders,
    const int* __restrict__ receivers,
    float* __restrict__ wexp, float* __restrict__ denomv)
{
    int id = blockIdx.x * 256 + threadIdx.x;   // N_EDGES*2 threads exactly
    int i = id >> 1, half = id & 1;
    int e = sorted[i];                         // coalesced (pairs share value)
    int s = senders[e], r = receivers[e];      // L2 gathers (3.2MB arrays)
    const uint4* qp = (const uint4*)&Q[(size_t)r * HID + half * 64];
    const uint4* kp = (const uint4*)&K[(size_t)s * HID + half * 64];
    float a0 = 0.f, a1 = 0.f;
    #pragma unroll
    for (int j = 0; j < 4; ++j) {              // head 2*half
        uint4 a = qp[j], b = kp[j];
        a0 += bflo(a.x) * bflo(b.x) + bfhi(a.x) * bfhi(b.x);
        a0 += bflo(a.y) * bflo(b.y) + bfhi(a.y) * bfhi(b.y);
        a0 += bflo(a.z) * bflo(b.z) + bfhi(a.z) * bfhi(b.z);
        a0 += bflo(a.w) * bflo(b.w) + bfhi(a.w) * bfhi(b.w);
    }
    #pragma unroll
    for (int j = 4; j < 8; ++j) {              // head 2*half+1
        uint4 a = qp[j], b = kp[j];
        a1 += bflo(a.x) * bflo(b.x) + bfhi(a.x) * bfhi(b.x);
        a1 += bflo(a.y) * bflo(b.y) + bfhi(a.y) * bfhi(b.y);
        a1 += bflo(a.z) * bflo(b.z) + bfhi(a.z) * bfhi(b.z);
        a1 += bflo(a.w) * bflo(b.w) + bfhi(a.w) * bfhi(b.w);
    }
    // softmax is shift-invariant; logits ~N(0,1) so skipping the max pass is safe
    const float sc = 0.17677669529663687f;     // 1/sqrt(32)
    float2 o = make_float2(expf(a0 * sc), expf(a1 * sc));
    *(float2*)&wexp[(size_t)e * 4 + half * 2] = o;   // scatter to edge order
    atomicAdd(&denomv[(size_t)r * 4 + half * 2], o.x);
    atomicAdd(&denomv[(size_t)r * 4 + half * 2 + 1], o.y);
}

// --- K5 v10: ORIGINAL edge order, fully streaming (v9 structure).
// Weights = wexp[e] (coalesced) * 0.25 * rcp(denomv[r]) (broadcast 16B gather
// from 800KB L2-hot array). Reads edges coalesced via wave-private LDS,
// Vp gather (L2/L3-hot 12.8MB), msg write COALESCED.
__global__ __launch_bounds__(256, 4) void edge_messages_v10(
    const float* __restrict__ edges, const u16* __restrict__ WeTg,
    const u16* __restrict__ Vp, const float* __restrict__ wexp,
    const float* __restrict__ denomv, const int* __restrict__ senders,
    const int* __restrict__ receivers, u16* __restrict__ msg)
{
    __shared__ __align__(16) u16 Ae[4][32 * 72];   // 18 KB, wave-private quadrants

    const int tid = threadIdx.x;
    const int wave = tid >> 6, lane = tid & 63;
    const int quad = lane >> 4, l15 = lane & 15;
    const int base = blockIdx.x * 128 + wave * 32;   // original edge id base

    // ---- per-edge metadata: coalesced / broadcast
    int snd8[8];
    float w8[8][4];
    #pragma unroll
    for (int idx = 0; idx < 8; ++idx) {
        int el = base + (idx >> 2) * 16 + quad * 4 + (idx & 3);
        snd8[idx] = senders[el];
        int r = receivers[el];
        float4 we = *(const float4*)&wexp[(size_t)el * 4];
        float4 dn = *(const float4*)&denomv[(size_t)r * 4];
        w8[idx][0] = we.x * 0.25f * __builtin_amdgcn_rcpf(dn.x);
        w8[idx][1] = we.y * 0.25f * __builtin_amdgcn_rcpf(dn.y);
        w8[idx][2] = we.z * 0.25f * __builtin_amdgcn_rcpf(dn.z);
        w8[idx][3] = we.w * 0.25f * __builtin_amdgcn_rcpf(dn.w);
    }

    // ---- wave-private staging: 32 edges x 64 k, coalesced within wave
    u16* As = &Ae[wave][0];
    #pragma unroll
    for (int it = 0; it < 8; ++it) {
        int idx = lane + it * 64;              // 512 float4s per wave
        int row = idx >> 4, k4 = (idx & 15) * 4;
        float4 v = *(const float4*)&edges[(size_t)(base + row) * D_EDGE + k4];
        ushort4 b;
        b.x = f2bf(v.x); b.y = f2bf(v.y); b.z = f2bf(v.z); b.w = f2bf(v.w);
        *(ushort4*)&As[row * 72 + k4] = b;
    }
    // no barrier: same-wave ds_write -> ds_read ordered by lgkmcnt

    bf16x8 afr[2][2];
    #pragma unroll
    for (int rt = 0; rt < 2; ++rt)
        #pragma unroll
        for (int ks = 0; ks < 2; ++ks)
            afr[rt][ks] = *(const bf16x8*)&Ae[wave][(rt * 16 + l15) * 72 + ks * 32 + quad * 8];

    #pragma unroll
    for (int p = 0; p < 2; ++p) {              // ct-parity pass; d = p*16 + l15
        const int d = p * 16 + l15;
        // Vp gather: all 4 head components in one 8B load; 16 lanes of a quad
        // read a 128B contiguous segment per idx
        ushort4 vp8[8];
        #pragma unroll
        for (int idx = 0; idx < 8; ++idx)
            vp8[idx] = *(const ushort4*)&Vp[(size_t)snd8[idx] * HID + d * 4];

        f32x4 acc[2][4];
        #pragma unroll
        for (int rt = 0; rt < 2; ++rt)
            #pragma unroll
            for (int c = 0; c < 4; ++c)
                acc[rt][c] = (f32x4){0.f, 0.f, 0.f, 0.f};

        #pragma unroll
        for (int ks = 0; ks < 2; ++ks) {
            #pragma unroll
            for (int c = 0; c < 4; ++c) {
                bf16x8 b = *(const bf16x8*)&WeTg[((2 * c + p) * 16 + l15) * 64 + ks * 32 + quad * 8];
                acc[0][c] = __builtin_amdgcn_mfma_f32_16x16x32_bf16(afr[0][ks], b, acc[0][c], 0, 0, 0);
                acc[1][c] = __builtin_amdgcn_mfma_f32_16x16x32_bf16(afr[1][ks], b, acc[1][c], 0, 0, 0);
            }
        }

        // epilogue: out_d = sum_h w_h * (E_h + V_h); COALESCED write
        #pragma unroll
        for (int idx = 0; idx < 8; ++idx) {
            int rt = idx >> 2, r = idx & 3;
            int el = base + rt * 16 + quad * 4 + r;
            float out = w8[idx][0] * (acc[rt][0][r] + bf2f(vp8[idx].x))
                      + w8[idx][1] * (acc[rt][1][r] + bf2f(vp8[idx].y))
                      + w8[idx][2] * (acc[rt][2][r] + bf2f(vp8[idx].z))
                      + w8[idx][3] * (acc[rt][3][r] + bf2f(vp8[idx].w));
            msg[(size_t)el * OUT_DIM + d] = f2bf(out);
        }
    }
}

// --- K6: per-node aggregate; msg gathered via sorted (64B full lines),
// base path precomputed in node_qkv_v3 (no GEMV, no nodes re-read).
__global__ __launch_bounds__(256) void aggregate4(
    const u16* __restrict__ msg, const float* __restrict__ baseout,
    const int* __restrict__ sorted, const int* __restrict__ startp,
    float* __restrict__ out)
{
    int id = blockIdx.x * 256 + threadIdx.x;   // N*32 threads exactly
    int n = id >> 5, d = id & 31;
    float acc = baseout[id];
    int s = startp[n], e = startp[n + 1];
    for (int i = s; i < e; ++i) {
        int el = sorted[i];                    // broadcast within 32-lane group
        acc += bf2f(msg[(size_t)el * OUT_DIM + d]);
    }
    out[id] = fmaxf(acc, 0.f);
}

// ---------------------------------------------------------------- launcher
extern "C" void kernel_launch(void* const* d_in, const int* in_sizes, int n_in,
                              void* d_out, int out_size, void* d_ws, size_t ws_size,
                              hipStream_t stream) {
    const float* nodes     = (const float*)d_in[0];
    const float* edges     = (const float*)d_in[1];
    const int*   senders   = (const int*)d_in[2];
    const int*   receivers = (const int*)d_in[3];
    const float* Wq = (const float*)d_in[4];
    const float* bq = (const float*)d_in[5];
    const float* Wk = (const float*)d_in[6];
    const float* bk = (const float*)d_in[7];
    const float* Wv = (const float*)d_in[8];
    const float* bv = (const float*)d_in[9];
    const float* We = (const float*)d_in[10];
    const float* Wu = (const float*)d_in[11];
    const float* bu = (const float*)d_in[12];
    float* out = (float*)d_out;

    // ---- workspace layout (all chunks 16B-aligned)
    char* p = (char*)d_ws;
    u16* Qb    = (u16*)p; p += (size_t)N_NODES * HID * 2;          // 12.8 MB
    u16* Kb    = (u16*)p; p += (size_t)N_NODES * HID * 2;          // 12.8 MB
    u16* Vperm = (u16*)p; p += (size_t)N_NODES * HID * 2;          // 12.8 MB
    u16* WT_all= (u16*)p; p += (size_t)(3 * HID * HID + OUT_DIM * HID) * 2;  // 104 KB
    u16* WeTg  = (u16*)p; p += (size_t)HID * D_EDGE * 2;           // 16 KB
    float* wexp = (float*)p; p += (size_t)N_EDGES * 4 * 4;         // 12.8 MB
    u16* msg   = (u16*)p; p += (size_t)N_EDGES * OUT_DIM * 2;      // 51.2 MB
    float* baseout = (float*)p; p += (size_t)N_NODES * OUT_DIM * 4;// 6.4 MB
    int* count  = (int*)p; p += (size_t)N_NODES * 4;               // count +
    float* denomv = (float*)p; p += (size_t)N_NODES * 4 * 4;       // denomv: contiguous, zeroed together
    int* incl   = (int*)p; p += (size_t)N_NODES * 4;
    int* startp = (int*)p; p += (size_t)(N_NODES + 4) * 4;
    int* cursor = (int*)p; p += (size_t)N_NODES * 4;
    int* sorted = (int*)p; p += (size_t)N_EDGES * 4;
    int* bsum   = (int*)p; p += 256 * 4;
    int* boff   = (int*)p; p += 256 * 4;

    const int SCAN_BLOCKS = (N_NODES + 255) / 256;   // 196
    const int ZERO_N = N_NODES + N_NODES * 4;        // count + denomv = 250000 ints

    hipLaunchKernelGGL(zero_i32, dim3((ZERO_N + 255) / 256), dim3(256), 0, stream,
                       count, ZERO_N);
    hipLaunchKernelGGL(hist_kernel, dim3(N_EDGES / 256), dim3(256), 0, stream,
                       receivers, count);
    hipLaunchKernelGGL(scan1, dim3(SCAN_BLOCKS), dim3(256), 0, stream, count, incl, bsum);
    hipLaunchKernelGGL(scan2, dim3(1), dim3(256), 0, stream, bsum, boff, SCAN_BLOCKS);
    hipLaunchKernelGGL(scan3, dim3(SCAN_BLOCKS), dim3(256), 0, stream,
                       incl, count, boff, startp, cursor);
    hipLaunchKernelGGL(scatter_v4, dim3(N_EDGES / 256), dim3(256), 0, stream,
                       receivers, cursor, sorted);
    hipLaunchKernelGGL(prep_weights, dim3(61440 / 256), dim3(256), 0, stream,
                       Wq, Wk, Wv, We, Wu, WT_all, WeTg);
    hipLaunchKernelGGL(node_qkv_v3, dim3((N_NODES + 127) / 128), dim3(256), 0, stream,
                       nodes, WT_all, bq, bk, bv, bu, Qb, Kb, Vperm, baseout);
    hipLaunchKernelGGL(edge_logits_v5, dim3(N_EDGES * 2 / 256), dim3(256), 0, stream,
                       Qb, Kb, sorted, senders, receivers, wexp, denomv);
    hipLaunchKernelGGL(edge_messages_v10, dim3(N_EDGES / 128), dim3(256), 0, stream,
                       edges, WeTg, Vperm, wexp, denomv, senders, receivers, msg);
    hipLaunchKernelGGL(aggregate4, dim3(N_NODES * OUT_DIM / 256), dim3(256), 0, stream,
                       msg, baseout, sorted, startp, out);
}

// Round 5
// 604.693 us; speedup vs baseline: 1.2220x; 1.2220x over previous
//
#include <hip/hip_runtime.h>
#include <math.h>

#define N_NODES 50000
#define N_EDGES 800000
#define D_FEAT 128
#define D_EDGE 64
#define HID 128
#define OUT_DIM 32

typedef unsigned short u16;
typedef short bf16x8 __attribute__((ext_vector_type(8)));
typedef float f32x4 __attribute__((ext_vector_type(4)));

__device__ __forceinline__ u16 f2bf(float x) {           // RNE fp32 -> bf16 bits
    unsigned u = __float_as_uint(x);
    unsigned r = (u >> 16) & 1u;
    return (u16)((u + 0x7FFFu + r) >> 16);
}
__device__ __forceinline__ float bf2f(u16 s) { return __uint_as_float(((unsigned)s) << 16); }
__device__ __forceinline__ float bflo(unsigned u) { return __uint_as_float(u << 16); }
__device__ __forceinline__ float bfhi(unsigned u) { return __uint_as_float(u & 0xFFFF0000u); }

__device__ __forceinline__ float dot16(uint4 a, uint4 b) {   // 8 bf16 pairs x2
    float s = 0.f;
    s += bflo(a.x) * bflo(b.x) + bfhi(a.x) * bfhi(b.x);
    s += bflo(a.y) * bflo(b.y) + bfhi(a.y) * bfhi(b.y);
    s += bflo(a.z) * bflo(b.z) + bfhi(a.z) * bfhi(b.z);
    s += bflo(a.w) * bflo(b.w) + bfhi(a.w) * bfhi(b.w);
    return s;
}

// ---------------------------------------------------------------- utilities
__global__ void zero_i32(int* __restrict__ p, int n) {
    int i = blockIdx.x * 256 + threadIdx.x;
    if (i < n) p[i] = 0;
}

// ---- prep: transpose+cvt weights to bf16 once.
// WT_all[m][c][k] (m=0,1,2 -> Wq,Wk,Wv; 128x128), then WuT[c][k] (32x128)
// appended at offset 49152; WeTg[c][k] (128x64).
__global__ void prep_weights(const float* __restrict__ Wq, const float* __restrict__ Wk,
                             const float* __restrict__ Wv, const float* __restrict__ We,
                             const float* __restrict__ Wu,
                             u16* __restrict__ WT_all, u16* __restrict__ WeTg) {
    int id = blockIdx.x * 256 + threadIdx.x;   // 61440 threads
    if (id < 49152) {
        int m = id >> 14, rem = id & 16383;
        int c = rem >> 7, k = rem & 127;
        const float* W = (m == 0) ? Wq : (m == 1) ? Wk : Wv;
        WT_all[id] = f2bf(W[k * HID + c]);
    } else if (id < 57344) {
        int j = id - 49152;                    // 8192: WeTg
        int c = j >> 6, k = j & 63;
        WeTg[j] = f2bf(We[k * HID + c]);
    } else {
        int j = id - 57344;                    // 4096: WuT [32][128]
        int c = j >> 7, k = j & 127;
        WT_all[49152 + j] = f2bf(Wu[k * OUT_DIM + c]);
    }
}

// ------------------------------------------------- K1: Q/K/V/base GEMM via MFMA
// ONE block computes Q,K,V AND nodes@Wu+bu for 128 nodes (nodes read once).
// Wave-private LDS staging -> no __syncthreads.
// V stored HEAD-INTERLEAVED: Vp[n][d*4+h]. baseout is f32 [n][32].
__global__ __launch_bounds__(256) void node_qkv_v3(
    const float* __restrict__ nodes, const u16* __restrict__ WT_all,
    const float* __restrict__ bq, const float* __restrict__ bk, const float* __restrict__ bv,
    const float* __restrict__ bu,
    u16* __restrict__ Q, u16* __restrict__ Kk, u16* __restrict__ Vp,
    float* __restrict__ baseout)
{
    __shared__ __align__(16) u16 Alds[4][32 * 136];   // 34.8 KB, wave-private quadrants

    const int tid = threadIdx.x;
    const int wave = tid >> 6, lane = tid & 63;
    const int quad = lane >> 4, l15 = lane & 15;
    const int rowbase = blockIdx.x * 128 + wave * 32;

    u16* As = &Alds[wave][0];
    // wave-private staging: 32 rows x 128 cols, coalesced within wave
    #pragma unroll
    for (int it = 0; it < 16; ++it) {
        int idx = lane + it * 64;              // 1024 float4s per wave
        int row = idx >> 5, k4 = (idx & 31) * 4;
        float4 v = make_float4(0.f, 0.f, 0.f, 0.f);
        if (rowbase + row < N_NODES)
            v = *(const float4*)&nodes[(size_t)(rowbase + row) * D_FEAT + k4];
        ushort4 b;
        b.x = f2bf(v.x); b.y = f2bf(v.y); b.z = f2bf(v.z); b.w = f2bf(v.w);
        *(ushort4*)&As[row * 136 + k4] = b;
    }
    // no barrier: same-wave ds_write -> ds_read ordered by lgkmcnt

    bf16x8 afr[2][4];
    #pragma unroll
    for (int rt = 0; rt < 2; ++rt)
        #pragma unroll
        for (int ks = 0; ks < 4; ++ks)
            afr[rt][ks] = *(const bf16x8*)&As[(rt * 16 + l15) * 136 + ks * 32 + quad * 8];

    #pragma unroll
    for (int m = 0; m < 3; ++m) {
        const u16* WT = WT_all + (size_t)m * 16384;
        const float* bvec = (m == 0) ? bq : (m == 1) ? bk : bv;
        u16* C = (m == 0) ? Q : (m == 1) ? Kk : Vp;

        f32x4 acc[2][8];
        #pragma unroll
        for (int rt = 0; rt < 2; ++rt)
            #pragma unroll
            for (int ct = 0; ct < 8; ++ct)
                acc[rt][ct] = (f32x4){0.f, 0.f, 0.f, 0.f};

        #pragma unroll
        for (int ks = 0; ks < 4; ++ks) {
            #pragma unroll
            for (int ct = 0; ct < 8; ++ct) {
                bf16x8 b = *(const bf16x8*)&WT[(ct * 16 + l15) * 128 + ks * 32 + quad * 8];
                acc[0][ct] = __builtin_amdgcn_mfma_f32_16x16x32_bf16(afr[0][ks], b, acc[0][ct], 0, 0, 0);
                acc[1][ct] = __builtin_amdgcn_mfma_f32_16x16x32_bf16(afr[1][ks], b, acc[1][ct], 0, 0, 0);
            }
        }

        // epilogue: C layout row=quad*4+r (+rt*16), col=ct*16+l15
        #pragma unroll
        for (int ct = 0; ct < 8; ++ct) {
            int cbase = ct * 16 + l15;
            float bias = bvec[cbase];
            int oidx = (m == 2) ? ((cbase & 31) * 4 + (cbase >> 5)) : cbase;
            #pragma unroll
            for (int rt = 0; rt < 2; ++rt)
                #pragma unroll
                for (int r = 0; r < 4; ++r) {
                    int n = rowbase + rt * 16 + quad * 4 + r;
                    if (n < N_NODES)
                        C[(size_t)n * HID + oidx] = f2bf(acc[rt][ct][r] + bias);
                }
        }
    }

    // ---- base pass: nodes@Wu + bu -> baseout f32 (32 cols)
    {
        const u16* WuT = WT_all + 49152;
        f32x4 accu[2][2];
        #pragma unroll
        for (int rt = 0; rt < 2; ++rt)
            #pragma unroll
            for (int ct = 0; ct < 2; ++ct)
                accu[rt][ct] = (f32x4){0.f, 0.f, 0.f, 0.f};
        #pragma unroll
        for (int ks = 0; ks < 4; ++ks) {
            #pragma unroll
            for (int ct = 0; ct < 2; ++ct) {
                bf16x8 b = *(const bf16x8*)&WuT[(ct * 16 + l15) * 128 + ks * 32 + quad * 8];
                accu[0][ct] = __builtin_amdgcn_mfma_f32_16x16x32_bf16(afr[0][ks], b, accu[0][ct], 0, 0, 0);
                accu[1][ct] = __builtin_amdgcn_mfma_f32_16x16x32_bf16(afr[1][ks], b, accu[1][ct], 0, 0, 0);
            }
        }
        #pragma unroll
        for (int ct = 0; ct < 2; ++ct) {
            int cbase = ct * 16 + l15;
            float bias = bu[cbase];
            #pragma unroll
            for (int rt = 0; rt < 2; ++rt)
                #pragma unroll
                for (int r = 0; r < 4; ++r) {
                    int n = rowbase + rt * 16 + quad * 4 + r;
                    if (n < N_NODES)
                        baseout[(size_t)n * OUT_DIM + cbase] = accu[rt][ct][r] + bias;
                }
        }
    }
}

// ---------------------------------------------- CSR build
__global__ void hist_kernel(const int* __restrict__ receivers, int* __restrict__ count) {
    int e = blockIdx.x * 256 + threadIdx.x;
    atomicAdd(&count[receivers[e]], 1);
}

__global__ __launch_bounds__(256) void scan1(const int* __restrict__ count,
                                             int* __restrict__ incl, int* __restrict__ bsum) {
    __shared__ int sh[256];
    int gid = blockIdx.x * 256 + threadIdx.x;
    int v = (gid < N_NODES) ? count[gid] : 0;
    sh[threadIdx.x] = v; __syncthreads();
    #pragma unroll
    for (int off = 1; off < 256; off <<= 1) {
        int t = (threadIdx.x >= off) ? sh[threadIdx.x - off] : 0;
        __syncthreads();
        sh[threadIdx.x] += t;
        __syncthreads();
    }
    if (gid < N_NODES) incl[gid] = sh[threadIdx.x];
    if (threadIdx.x == 255) bsum[blockIdx.x] = sh[255];
}

__global__ __launch_bounds__(256) void scan2(const int* __restrict__ bsum,
                                             int* __restrict__ boff, int nblocks) {
    __shared__ int sh[256];
    int v = (threadIdx.x < nblocks) ? bsum[threadIdx.x] : 0;
    sh[threadIdx.x] = v; __syncthreads();
    #pragma unroll
    for (int off = 1; off < 256; off <<= 1) {
        int t = (threadIdx.x >= off) ? sh[threadIdx.x - off] : 0;
        __syncthreads();
        sh[threadIdx.x] += t;
        __syncthreads();
    }
    boff[threadIdx.x] = sh[threadIdx.x] - v;   // exclusive
}

__global__ __launch_bounds__(256) void scan3(const int* __restrict__ incl,
                                             const int* __restrict__ count,
                                             const int* __restrict__ boff,
                                             int* __restrict__ startp, int* __restrict__ cursor) {
    int gid = blockIdx.x * 256 + threadIdx.x;
    if (gid < N_NODES) {
        int ex = incl[gid] - count[gid] + boff[blockIdx.x];
        startp[gid] = ex;
        cursor[gid] = ex;
    }
    if (gid == 0) startp[N_NODES] = N_EDGES;
}

// v5: CSR-ordered edge id + sender arrays (srecv dropped: the softmax kernel
// is wave-per-node so it knows its receiver implicitly).
__global__ void scatter_v5(const int* __restrict__ senders, const int* __restrict__ receivers,
                           int* __restrict__ cursor, int* __restrict__ sorted,
                           int* __restrict__ ssend) {
    int e = blockIdx.x * 256 + threadIdx.x;
    int r = receivers[e];
    int s = senders[e];
    int pos = atomicAdd(&cursor[r], 1);
    sorted[pos] = e;
    ssend[pos] = s;
}

// ------------- K3+K4 merged: wave-per-node softmax.
// lane = e_local*4 + h. Q row loaded ONCE per wave; K rows 256B contiguous per
// 4 lanes; denominator via 4-step shfl_xor butterfly (no wbuf round-trip);
// normalized weight scattered straight to wnorm[e*4+h] (edge order) so
// edge_messages reads coalesced. exp values stay in registers for degree<=96
// (Poisson(16): always); correct global spill path beyond.
__global__ __launch_bounds__(256) void node_softmax(
    const u16* __restrict__ Q, const u16* __restrict__ K,
    const int* __restrict__ startp, const int* __restrict__ sorted,
    const int* __restrict__ ssend, float* __restrict__ wspill,
    float* __restrict__ wnorm)
{
    const int wid = (blockIdx.x * 256 + threadIdx.x) >> 6;   // wave id = node (50000 exact)
    const int lane = threadIdx.x & 63;
    const int h = lane & 3, el = lane >> 2;
    const int s0 = startp[wid];
    const int deg = startp[wid + 1] - s0;
    if (deg == 0) return;
    const int nc = (deg + 15) >> 4;
    const float sc = 0.17677669529663687f;                   // 1/sqrt(32)

    // Q slice for this head: 32 bf16 = 4 uint4 (wave-uniform row)
    const uint4* qp = (const uint4*)&Q[(size_t)wid * HID + h * 32];
    const uint4 q0 = qp[0], q1 = qp[1], q2 = qp[2], q3 = qp[3];

    float expv0 = 0.f, expv1 = 0.f, expv2 = 0.f, expv3 = 0.f, expv4 = 0.f, expv5 = 0.f;
    float dtot = 0.f;

    #pragma unroll
    for (int c = 0; c < 6; ++c) {
        if (c >= nc) break;
        int sl = c * 16 + el;
        float w = 0.f;
        if (sl < deg) {
            int s = ssend[s0 + sl];
            const uint4* kp = (const uint4*)&K[(size_t)s * HID + h * 32];
            float a = dot16(q0, kp[0]) + dot16(q1, kp[1])
                    + dot16(q2, kp[2]) + dot16(q3, kp[3]);
            w = expf(a * sc);
        }
        if (c == 0) expv0 = w; else if (c == 1) expv1 = w; else if (c == 2) expv2 = w;
        else if (c == 3) expv3 = w; else if (c == 4) expv4 = w; else expv5 = w;
        float t = w;
        t += __shfl_xor(t, 4); t += __shfl_xor(t, 8);
        t += __shfl_xor(t, 16); t += __shfl_xor(t, 32);
        dtot += t;
    }
    // ultra-rare path: degree > 96 (never for Poisson(16); kept for correctness)
    for (int c = 6; c < nc; ++c) {
        int sl = c * 16 + el;
        float w = 0.f;
        if (sl < deg) {
            int s = ssend[s0 + sl];
            const uint4* kp = (const uint4*)&K[(size_t)s * HID + h * 32];
            float a = dot16(q0, kp[0]) + dot16(q1, kp[1])
                    + dot16(q2, kp[2]) + dot16(q3, kp[3]);
            w = expf(a * sc);
            wspill[(size_t)(s0 + sl) * 4 + h] = w;
        }
        float t = w;
        t += __shfl_xor(t, 4); t += __shfl_xor(t, 8);
        t += __shfl_xor(t, 16); t += __shfl_xor(t, 32);
        dtot += t;
    }

    const float inv = 0.25f / dtot;                          // fold head-mean

    #pragma unroll
    for (int c = 0; c < 6; ++c) {
        if (c >= nc) break;
        int sl = c * 16 + el;
        if (sl < deg) {
            float w = (c == 0) ? expv0 : (c == 1) ? expv1 : (c == 2) ? expv2
                    : (c == 3) ? expv3 : (c == 4) ? expv4 : expv5;
            int e = sorted[s0 + sl];
            wnorm[(size_t)e * 4 + h] = w * inv;
        }
    }
    if (nc > 6) {
        asm volatile("s_waitcnt vmcnt(0)" ::: "memory");     // spill stores visible
        for (int c = 6; c < nc; ++c) {
            int sl = c * 16 + el;
            if (sl < deg) {
                float w = wspill[(size_t)(s0 + sl) * 4 + h];
                int e = sorted[s0 + sl];
                wnorm[(size_t)e * 4 + h] = w * inv;
            }
        }
    }
}

// --- K5 v9: ORIGINAL edge order, fully streaming.
// Reads: edges (coalesced, wave-private LDS staging), wnorm (coalesced),
// senders (coalesced), Vp (gather, L2/L3-hot 12.8MB), WeTg (L1).
// Writes: msg[e] COALESCED (original order).
__global__ __launch_bounds__(256) void edge_messages_v9(
    const float* __restrict__ edges, const u16* __restrict__ WeTg,
    const u16* __restrict__ Vp, const float* __restrict__ wnorm,
    const int* __restrict__ senders, u16* __restrict__ msg)
{
    __shared__ __align__(16) u16 Ae[4][32 * 72];   // 18 KB, wave-private quadrants

    const int tid = threadIdx.x;
    const int wave = tid >> 6, lane = tid & 63;
    const int quad = lane >> 4, l15 = lane & 15;
    const int base = blockIdx.x * 128 + wave * 32;   // original edge id base

    // ---- per-edge metadata: all coalesced now
    int snd8[8];
    float w8[8][4];
    #pragma unroll
    for (int idx = 0; idx < 8; ++idx) {
        int el = base + (idx >> 2) * 16 + quad * 4 + (idx & 3);
        snd8[idx] = senders[el];
        float4 w = *(const float4*)&wnorm[(size_t)el * 4];
        w8[idx][0] = w.x; w8[idx][1] = w.y; w8[idx][2] = w.z; w8[idx][3] = w.w;
    }

    // ---- wave-private staging: 32 edges x 64 k, coalesced within wave
    u16* As = &Ae[wave][0];
    #pragma unroll
    for (int it = 0; it < 8; ++it) {
        int idx = lane + it * 64;              // 512 float4s per wave
        int row = idx >> 4, k4 = (idx & 15) * 4;
        float4 v = *(const float4*)&edges[(size_t)(base + row) * D_EDGE + k4];
        ushort4 b;
        b.x = f2bf(v.x); b.y = f2bf(v.y); b.z = f2bf(v.z); b.w = f2bf(v.w);
        *(ushort4*)&As[row * 72 + k4] = b;
    }
    // no barrier: same-wave ds_write -> ds_read ordered by lgkmcnt

    bf16x8 afr[2][2];
    #pragma unroll
    for (int rt = 0; rt < 2; ++rt)
        #pragma unroll
        for (int ks = 0; ks < 2; ++ks)
            afr[rt][ks] = *(const bf16x8*)&As[(rt * 16 + l15) * 72 + ks * 32 + quad * 8];

    #pragma unroll
    for (int p = 0; p < 2; ++p) {              // ct-parity pass; d = p*16 + l15
        const int d = p * 16 + l15;
        // Vp gather: all 4 head components in one 8B load; 16 lanes of a quad
        // read a 128B contiguous segment per idx
        ushort4 vp8[8];
        #pragma unroll
        for (int idx = 0; idx < 8; ++idx)
            vp8[idx] = *(const ushort4*)&Vp[(size_t)snd8[idx] * HID + d * 4];

        f32x4 acc[2][4];
        #pragma unroll
        for (int rt = 0; rt < 2; ++rt)
            #pragma unroll
            for (int c = 0; c < 4; ++c)
                acc[rt][c] = (f32x4){0.f, 0.f, 0.f, 0.f};

        #pragma unroll
        for (int ks = 0; ks < 2; ++ks) {
            #pragma unroll
            for (int c = 0; c < 4; ++c) {
                bf16x8 b = *(const bf16x8*)&WeTg[((2 * c + p) * 16 + l15) * 64 + ks * 32 + quad * 8];
                acc[0][c] = __builtin_amdgcn_mfma_f32_16x16x32_bf16(afr[0][ks], b, acc[0][c], 0, 0, 0);
                acc[1][c] = __builtin_amdgcn_mfma_f32_16x16x32_bf16(afr[1][ks], b, acc[1][c], 0, 0, 0);
            }
        }

        // epilogue: out_d = sum_h w_h * (E_h + V_h); COALESCED write
        #pragma unroll
        for (int idx = 0; idx < 8; ++idx) {
            int rt = idx >> 2, r = idx & 3;
            int el = base + rt * 16 + quad * 4 + r;
            float out = w8[idx][0] * (acc[rt][0][r] + bf2f(vp8[idx].x))
                      + w8[idx][1] * (acc[rt][1][r] + bf2f(vp8[idx].y))
                      + w8[idx][2] * (acc[rt][2][r] + bf2f(vp8[idx].z))
                      + w8[idx][3] * (acc[rt][3][r] + bf2f(vp8[idx].w));
            msg[(size_t)el * OUT_DIM + d] = f2bf(out);
        }
    }
}

// --- K6: per-node aggregate; msg gathered via sorted (64B full lines),
// base path precomputed in node_qkv_v3 (no GEMV, no nodes re-read).
__global__ __launch_bounds__(256) void aggregate4(
    const u16* __restrict__ msg, const float* __restrict__ baseout,
    const int* __restrict__ sorted, const int* __restrict__ startp,
    float* __restrict__ out)
{
    int id = blockIdx.x * 256 + threadIdx.x;   // N*32 threads exactly
    int n = id >> 5, d = id & 31;
    float acc = baseout[id];
    int s = startp[n], e = startp[n + 1];
    for (int i = s; i < e; ++i) {
        int el = sorted[i];                    // broadcast within 32-lane group
        acc += bf2f(msg[(size_t)el * OUT_DIM + d]);
    }
    out[id] = fmaxf(acc, 0.f);
}

// ---------------------------------------------------------------- launcher
extern "C" void kernel_launch(void* const* d_in, const int* in_sizes, int n_in,
                              void* d_out, int out_size, void* d_ws, size_t ws_size,
                              hipStream_t stream) {
    const float* nodes     = (const float*)d_in[0];
    const float* edges     = (const float*)d_in[1];
    const int*   senders   = (const int*)d_in[2];
    const int*   receivers = (const int*)d_in[3];
    const float* Wq = (const float*)d_in[4];
    const float* bq = (const float*)d_in[5];
    const float* Wk = (const float*)d_in[6];
    const float* bk = (const float*)d_in[7];
    const float* Wv = (const float*)d_in[8];
    const float* bv = (const float*)d_in[9];
    const float* We = (const float*)d_in[10];
    const float* Wu = (const float*)d_in[11];
    const float* bu = (const float*)d_in[12];
    float* out = (float*)d_out;

    // ---- workspace layout (all chunks 16B-aligned)
    char* p = (char*)d_ws;
    u16* Qb    = (u16*)p; p += (size_t)N_NODES * HID * 2;          // 12.8 MB
    u16* Kb    = (u16*)p; p += (size_t)N_NODES * HID * 2;          // 12.8 MB
    u16* Vperm = (u16*)p; p += (size_t)N_NODES * HID * 2;          // 12.8 MB
    u16* WT_all= (u16*)p; p += (size_t)(3 * HID * HID + OUT_DIM * HID) * 2;  // 104 KB
    u16* WeTg  = (u16*)p; p += (size_t)HID * D_EDGE * 2;           // 16 KB
    float* wspill = (float*)p; p += (size_t)N_EDGES * 4 * 4;       // 12.8 MB (rare path)
    float* wnorm  = (float*)p; p += (size_t)N_EDGES * 4 * 4;       // 12.8 MB
    u16* msg   = (u16*)p; p += (size_t)N_EDGES * OUT_DIM * 2;      // 51.2 MB
    float* baseout = (float*)p; p += (size_t)N_NODES * OUT_DIM * 4;// 6.4 MB
    int* count  = (int*)p; p += (size_t)N_NODES * 4;
    int* incl   = (int*)p; p += (size_t)N_NODES * 4;
    int* startp = (int*)p; p += (size_t)(N_NODES + 4) * 4;
    int* cursor = (int*)p; p += (size_t)N_NODES * 4;
    int* sorted = (int*)p; p += (size_t)N_EDGES * 4;
    int* ssend  = (int*)p; p += (size_t)N_EDGES * 4;
    int* bsum   = (int*)p; p += 256 * 4;
    int* boff   = (int*)p; p += 256 * 4;

    const int SCAN_BLOCKS = (N_NODES + 255) / 256;   // 196

    hipLaunchKernelGGL(zero_i32, dim3(SCAN_BLOCKS), dim3(256), 0, stream, count, N_NODES);
    hipLaunchKernelGGL(hist_kernel, dim3(N_EDGES / 256), dim3(256), 0, stream,
                       receivers, count);
    hipLaunchKernelGGL(scan1, dim3(SCAN_BLOCKS), dim3(256), 0, stream, count, incl, bsum);
    hipLaunchKernelGGL(scan2, dim3(1), dim3(256), 0, stream, bsum, boff, SCAN_BLOCKS);
    hipLaunchKernelGGL(scan3, dim3(SCAN_BLOCKS), dim3(256), 0, stream,
                       incl, count, boff, startp, cursor);
    hipLaunchKernelGGL(scatter_v5, dim3(N_EDGES / 256), dim3(256), 0, stream,
                       senders, receivers, cursor, sorted, ssend);
    hipLaunchKernelGGL(prep_weights, dim3(61440 / 256), dim3(256), 0, stream,
                       Wq, Wk, Wv, We, Wu, WT_all, WeTg);
    hipLaunchKernelGGL(node_qkv_v3, dim3((N_NODES + 127) / 128), dim3(256), 0, stream,
                       nodes, WT_all, bq, bk, bv, bu, Qb, Kb, Vperm, baseout);
    hipLaunchKernelGGL(node_softmax, dim3(N_NODES / 4), dim3(256), 0, stream,
                       Qb, Kb, startp, sorted, ssend, wspill, wnorm);
    hipLaunchKernelGGL(edge_messages_v9, dim3(N_EDGES / 128), dim3(256), 0, stream,
                       edges, WeTg, Vperm, wnorm, senders, msg);
    hipLaunchKernelGGL(aggregate4, dim3(N_NODES * OUT_DIM / 256), dim3(256), 0, stream,
                       msg, baseout, sorted, startp, out);
}

// Round 6
// 586.398 us; speedup vs baseline: 1.2601x; 1.0312x over previous
//
#include <hip/hip_runtime.h>
#include <math.h>

#define N_NODES 50000
#define N_EDGES 800000
#define D_FEAT 128
#define D_EDGE 64
#define HID 128
#define OUT_DIM 32

typedef unsigned short u16;
typedef short bf16x8 __attribute__((ext_vector_type(8)));
typedef float f32x4 __attribute__((ext_vector_type(4)));

__device__ __forceinline__ u16 f2bf(float x) {           // RNE fp32 -> bf16 bits
    unsigned u = __float_as_uint(x);
    unsigned r = (u >> 16) & 1u;
    return (u16)((u + 0x7FFFu + r) >> 16);
}
__device__ __forceinline__ float bf2f(u16 s) { return __uint_as_float(((unsigned)s) << 16); }
__device__ __forceinline__ float bflo(unsigned u) { return __uint_as_float(u << 16); }
__device__ __forceinline__ float bfhi(unsigned u) { return __uint_as_float(u & 0xFFFF0000u); }

__device__ __forceinline__ float dot16(uint4 a, uint4 b) {   // 8 bf16 pairs x2
    float s = 0.f;
    s += bflo(a.x) * bflo(b.x) + bfhi(a.x) * bfhi(b.x);
    s += bflo(a.y) * bflo(b.y) + bfhi(a.y) * bfhi(b.y);
    s += bflo(a.z) * bflo(b.z) + bfhi(a.z) * bfhi(b.z);
    s += bflo(a.w) * bflo(b.w) + bfhi(a.w) * bfhi(b.w);
    return s;
}

// ---------------------------------------------------------------- utilities
__global__ void zero_i32(int* __restrict__ p, int n) {
    int i = blockIdx.x * 256 + threadIdx.x;
    if (i < n) p[i] = 0;
}

// ---- prep: transpose+cvt weights to bf16 once.
// WT_all[m][c][k] (m=0,1,2 -> Wq,Wk,Wv; 128x128), then WuT[c][k] (32x128)
// appended at offset 49152; WeTg[c][k] (128x64).
__global__ void prep_weights(const float* __restrict__ Wq, const float* __restrict__ Wk,
                             const float* __restrict__ Wv, const float* __restrict__ We,
                             const float* __restrict__ Wu,
                             u16* __restrict__ WT_all, u16* __restrict__ WeTg) {
    int id = blockIdx.x * 256 + threadIdx.x;   // 61440 threads
    if (id < 49152) {
        int m = id >> 14, rem = id & 16383;
        int c = rem >> 7, k = rem & 127;
        const float* W = (m == 0) ? Wq : (m == 1) ? Wk : Wv;
        WT_all[id] = f2bf(W[k * HID + c]);
    } else if (id < 57344) {
        int j = id - 49152;                    // 8192: WeTg
        int c = j >> 6, k = j & 63;
        WeTg[j] = f2bf(We[k * HID + c]);
    } else {
        int j = id - 57344;                    // 4096: WuT [32][128]
        int c = j >> 7, k = j & 127;
        WT_all[49152 + j] = f2bf(Wu[k * OUT_DIM + c]);
    }
}

// ------------------------------------------------- K1: Q/K/V/base GEMM via MFMA
// v4: NO LDS. A-fragments loaded directly from global in the MFMA layout:
// per (rt,ks) the wave reads 16 CONSECUTIVE rows x 128B contiguous chunks
// (fully coalesced). Fragments live in VGPRs, reused across all 4 GEMMs.
// V stored for edge_messages' paired gather: Vp2[n][d15*8 + p*4 + h]
// (d = p*16+d15). baseout is f32 [n][32].
__global__ __launch_bounds__(256) void node_qkv_v4(
    const float* __restrict__ nodes, const u16* __restrict__ WT_all,
    const float* __restrict__ bq, const float* __restrict__ bk, const float* __restrict__ bv,
    const float* __restrict__ bu,
    u16* __restrict__ Q, u16* __restrict__ Kk, u16* __restrict__ Vp,
    float* __restrict__ baseout)
{
    const int tid = threadIdx.x;
    const int wave = tid >> 6, lane = tid & 63;
    const int quad = lane >> 4, l15 = lane & 15;
    const int rowbase = blockIdx.x * 128 + wave * 32;

    // ---- A-fragments direct from global (fp32 -> bf16 in-register)
    bf16x8 afr[2][4];
    #pragma unroll
    for (int rt = 0; rt < 2; ++rt) {
        int row = rowbase + rt * 16 + l15;
        bool ok = row < N_NODES;
        const float* rp = &nodes[(size_t)row * D_FEAT];
        #pragma unroll
        for (int ks = 0; ks < 4; ++ks) {
            float4 v0 = make_float4(0.f, 0.f, 0.f, 0.f);
            float4 v1 = make_float4(0.f, 0.f, 0.f, 0.f);
            if (ok) {
                v0 = *(const float4*)(rp + ks * 32 + quad * 8);
                v1 = *(const float4*)(rp + ks * 32 + quad * 8 + 4);
            }
            bf16x8 a;
            a[0] = (short)f2bf(v0.x); a[1] = (short)f2bf(v0.y);
            a[2] = (short)f2bf(v0.z); a[3] = (short)f2bf(v0.w);
            a[4] = (short)f2bf(v1.x); a[5] = (short)f2bf(v1.y);
            a[6] = (short)f2bf(v1.z); a[7] = (short)f2bf(v1.w);
            afr[rt][ks] = a;
        }
    }

    #pragma unroll
    for (int m = 0; m < 3; ++m) {
        const u16* WT = WT_all + (size_t)m * 16384;
        const float* bvec = (m == 0) ? bq : (m == 1) ? bk : bv;
        u16* C = (m == 0) ? Q : (m == 1) ? Kk : Vp;

        f32x4 acc[2][8];
        #pragma unroll
        for (int rt = 0; rt < 2; ++rt)
            #pragma unroll
            for (int ct = 0; ct < 8; ++ct)
                acc[rt][ct] = (f32x4){0.f, 0.f, 0.f, 0.f};

        #pragma unroll
        for (int ks = 0; ks < 4; ++ks) {
            #pragma unroll
            for (int ct = 0; ct < 8; ++ct) {
                bf16x8 b = *(const bf16x8*)&WT[(ct * 16 + l15) * 128 + ks * 32 + quad * 8];
                acc[0][ct] = __builtin_amdgcn_mfma_f32_16x16x32_bf16(afr[0][ks], b, acc[0][ct], 0, 0, 0);
                acc[1][ct] = __builtin_amdgcn_mfma_f32_16x16x32_bf16(afr[1][ks], b, acc[1][ct], 0, 0, 0);
            }
        }

        // epilogue: C layout row=quad*4+r (+rt*16), col=ct*16+l15
        #pragma unroll
        for (int ct = 0; ct < 8; ++ct) {
            int cbase = ct * 16 + l15;
            float bias = bvec[cbase];
            int oidx = cbase;
            if (m == 2) {                      // Vp2: h=cbase>>5, d=cbase&31
                int h = cbase >> 5, d = cbase & 31;
                oidx = (d & 15) * 8 + (d >> 4) * 4 + h;
            }
            #pragma unroll
            for (int rt = 0; rt < 2; ++rt)
                #pragma unroll
                for (int r = 0; r < 4; ++r) {
                    int n = rowbase + rt * 16 + quad * 4 + r;
                    if (n < N_NODES)
                        C[(size_t)n * HID + oidx] = f2bf(acc[rt][ct][r] + bias);
                }
        }
    }

    // ---- base pass: nodes@Wu + bu -> baseout f32 (32 cols)
    {
        const u16* WuT = WT_all + 49152;
        f32x4 accu[2][2];
        #pragma unroll
        for (int rt = 0; rt < 2; ++rt)
            #pragma unroll
            for (int ct = 0; ct < 2; ++ct)
                accu[rt][ct] = (f32x4){0.f, 0.f, 0.f, 0.f};
        #pragma unroll
        for (int ks = 0; ks < 4; ++ks) {
            #pragma unroll
            for (int ct = 0; ct < 2; ++ct) {
                bf16x8 b = *(const bf16x8*)&WuT[(ct * 16 + l15) * 128 + ks * 32 + quad * 8];
                accu[0][ct] = __builtin_amdgcn_mfma_f32_16x16x32_bf16(afr[0][ks], b, accu[0][ct], 0, 0, 0);
                accu[1][ct] = __builtin_amdgcn_mfma_f32_16x16x32_bf16(afr[1][ks], b, accu[1][ct], 0, 0, 0);
            }
        }
        #pragma unroll
        for (int ct = 0; ct < 2; ++ct) {
            int cbase = ct * 16 + l15;
            float bias = bu[cbase];
            #pragma unroll
            for (int rt = 0; rt < 2; ++rt)
                #pragma unroll
                for (int r = 0; r < 4; ++r) {
                    int n = rowbase + rt * 16 + quad * 4 + r;
                    if (n < N_NODES)
                        baseout[(size_t)n * OUT_DIM + cbase] = accu[rt][ct][r] + bias;
                }
        }
    }
}

// ---------------------------------------------- CSR build
__global__ void hist_kernel(const int* __restrict__ receivers, int* __restrict__ count) {
    int e = blockIdx.x * 256 + threadIdx.x;
    atomicAdd(&count[receivers[e]], 1);
}

__global__ __launch_bounds__(256) void scan1(const int* __restrict__ count,
                                             int* __restrict__ incl, int* __restrict__ bsum) {
    __shared__ int sh[256];
    int gid = blockIdx.x * 256 + threadIdx.x;
    int v = (gid < N_NODES) ? count[gid] : 0;
    sh[threadIdx.x] = v; __syncthreads();
    #pragma unroll
    for (int off = 1; off < 256; off <<= 1) {
        int t = (threadIdx.x >= off) ? sh[threadIdx.x - off] : 0;
        __syncthreads();
        sh[threadIdx.x] += t;
        __syncthreads();
    }
    if (gid < N_NODES) incl[gid] = sh[threadIdx.x];
    if (threadIdx.x == 255) bsum[blockIdx.x] = sh[255];
}

__global__ __launch_bounds__(256) void scan2(const int* __restrict__ bsum,
                                             int* __restrict__ boff, int nblocks) {
    __shared__ int sh[256];
    int v = (threadIdx.x < nblocks) ? bsum[threadIdx.x] : 0;
    sh[threadIdx.x] = v; __syncthreads();
    #pragma unroll
    for (int off = 1; off < 256; off <<= 1) {
        int t = (threadIdx.x >= off) ? sh[threadIdx.x - off] : 0;
        __syncthreads();
        sh[threadIdx.x] += t;
        __syncthreads();
    }
    boff[threadIdx.x] = sh[threadIdx.x] - v;   // exclusive
}

__global__ __launch_bounds__(256) void scan3(const int* __restrict__ incl,
                                             const int* __restrict__ count,
                                             const int* __restrict__ boff,
                                             int* __restrict__ startp, int* __restrict__ cursor) {
    int gid = blockIdx.x * 256 + threadIdx.x;
    if (gid < N_NODES) {
        int ex = incl[gid] - count[gid] + boff[blockIdx.x];
        startp[gid] = ex;
        cursor[gid] = ex;
    }
    if (gid == 0) startp[N_NODES] = N_EDGES;
}

// v5: CSR-ordered edge id + sender arrays.
__global__ void scatter_v5(const int* __restrict__ senders, const int* __restrict__ receivers,
                           int* __restrict__ cursor, int* __restrict__ sorted,
                           int* __restrict__ ssend) {
    int e = blockIdx.x * 256 + threadIdx.x;
    int r = receivers[e];
    int s = senders[e];
    int pos = atomicAdd(&cursor[r], 1);
    sorted[pos] = e;
    ssend[pos] = s;
}

// ------------- K3+K4 merged: wave-per-node softmax.
// lane = e_local*4 + h. Q row loaded ONCE per wave; K rows 256B contiguous per
// 4 lanes; denominator via shfl_xor butterfly; normalized weight scattered
// straight to wnorm[e*4+h] (edge order). Register exp cache for degree<=96.
__global__ __launch_bounds__(256) void node_softmax(
    const u16* __restrict__ Q, const u16* __restrict__ K,
    const int* __restrict__ startp, const int* __restrict__ sorted,
    const int* __restrict__ ssend, float* __restrict__ wspill,
    float* __restrict__ wnorm)
{
    const int wid = (blockIdx.x * 256 + threadIdx.x) >> 6;   // wave id = node (50000 exact)
    const int lane = threadIdx.x & 63;
    const int h = lane & 3, el = lane >> 2;
    const int s0 = startp[wid];
    const int deg = startp[wid + 1] - s0;
    if (deg == 0) return;
    const int nc = (deg + 15) >> 4;
    const float sc = 0.17677669529663687f;                   // 1/sqrt(32)

    // Q slice for this head: 32 bf16 = 4 uint4 (wave-uniform row)
    const uint4* qp = (const uint4*)&Q[(size_t)wid * HID + h * 32];
    const uint4 q0 = qp[0], q1 = qp[1], q2 = qp[2], q3 = qp[3];

    float expv0 = 0.f, expv1 = 0.f, expv2 = 0.f, expv3 = 0.f, expv4 = 0.f, expv5 = 0.f;
    float dtot = 0.f;

    #pragma unroll
    for (int c = 0; c < 6; ++c) {
        if (c >= nc) break;
        int sl = c * 16 + el;
        float w = 0.f;
        if (sl < deg) {
            int s = ssend[s0 + sl];
            const uint4* kp = (const uint4*)&K[(size_t)s * HID + h * 32];
            float a = dot16(q0, kp[0]) + dot16(q1, kp[1])
                    + dot16(q2, kp[2]) + dot16(q3, kp[3]);
            w = expf(a * sc);
        }
        if (c == 0) expv0 = w; else if (c == 1) expv1 = w; else if (c == 2) expv2 = w;
        else if (c == 3) expv3 = w; else if (c == 4) expv4 = w; else expv5 = w;
        float t = w;
        t += __shfl_xor(t, 4); t += __shfl_xor(t, 8);
        t += __shfl_xor(t, 16); t += __shfl_xor(t, 32);
        dtot += t;
    }
    // ultra-rare path: degree > 96 (kept for correctness)
    for (int c = 6; c < nc; ++c) {
        int sl = c * 16 + el;
        float w = 0.f;
        if (sl < deg) {
            int s = ssend[s0 + sl];
            const uint4* kp = (const uint4*)&K[(size_t)s * HID + h * 32];
            float a = dot16(q0, kp[0]) + dot16(q1, kp[1])
                    + dot16(q2, kp[2]) + dot16(q3, kp[3]);
            w = expf(a * sc);
            wspill[(size_t)(s0 + sl) * 4 + h] = w;
        }
        float t = w;
        t += __shfl_xor(t, 4); t += __shfl_xor(t, 8);
        t += __shfl_xor(t, 16); t += __shfl_xor(t, 32);
        dtot += t;
    }

    const float inv = 0.25f / dtot;                          // fold head-mean

    #pragma unroll
    for (int c = 0; c < 6; ++c) {
        if (c >= nc) break;
        int sl = c * 16 + el;
        if (sl < deg) {
            float w = (c == 0) ? expv0 : (c == 1) ? expv1 : (c == 2) ? expv2
                    : (c == 3) ? expv3 : (c == 4) ? expv4 : expv5;
            int e = sorted[s0 + sl];
            wnorm[(size_t)e * 4 + h] = w * inv;
        }
    }
    if (nc > 6) {
        asm volatile("s_waitcnt vmcnt(0)" ::: "memory");     // spill stores visible
        for (int c = 6; c < nc; ++c) {
            int sl = c * 16 + el;
            if (sl < deg) {
                float w = wspill[(size_t)(s0 + sl) * 4 + h];
                int e = sorted[s0 + sl];
                wnorm[(size_t)e * 4 + h] = w * inv;
            }
        }
    }
}

// --- K5 v11: ORIGINAL edge order, NO LDS.
// A-fragments direct from global (16 consecutive rows x 128B per instr --
// fully coalesced; this is why v8's version failed and this one shouldn't:
// rows here are sequential, not gathered). Vp2 layout gives ONE 16B gather
// per idx covering both p-passes (8 gathers instead of 16), all hoisted to
// the top so they overlap the edges loads. msg write COALESCED.
__global__ __launch_bounds__(256) void edge_messages_v11(
    const float* __restrict__ edges, const u16* __restrict__ WeTg,
    const u16* __restrict__ Vp2, const float* __restrict__ wnorm,
    const int* __restrict__ senders, u16* __restrict__ msg)
{
    const int tid = threadIdx.x;
    const int wave = tid >> 6, lane = tid & 63;
    const int quad = lane >> 4, l15 = lane & 15;
    const int base = blockIdx.x * 128 + wave * 32;   // original edge id base

    // ---- sender ids -> issue all 8 Vp gathers ASAP (longest latency chain)
    int snd8[8];
    #pragma unroll
    for (int idx = 0; idx < 8; ++idx) {
        int el = base + (idx >> 2) * 16 + quad * 4 + (idx & 3);
        snd8[idx] = senders[el];
    }
    uint4 vpg[8];                               // 16B/lane: [p0 h0..3, p1 h0..3]
    #pragma unroll
    for (int idx = 0; idx < 8; ++idx)
        vpg[idx] = *(const uint4*)&Vp2[(size_t)snd8[idx] * HID + l15 * 8];

    // ---- attention weights (coalesced)
    float w8[8][4];
    #pragma unroll
    for (int idx = 0; idx < 8; ++idx) {
        int el = base + (idx >> 2) * 16 + quad * 4 + (idx & 3);
        float4 w = *(const float4*)&wnorm[(size_t)el * 4];
        w8[idx][0] = w.x; w8[idx][1] = w.y; w8[idx][2] = w.z; w8[idx][3] = w.w;
    }

    // ---- A-fragments direct from global (coalesced, sequential rows)
    bf16x8 afr[2][2];
    #pragma unroll
    for (int rt = 0; rt < 2; ++rt) {
        const float* rp = &edges[(size_t)(base + rt * 16 + l15) * D_EDGE];
        #pragma unroll
        for (int ks = 0; ks < 2; ++ks) {
            float4 v0 = *(const float4*)(rp + ks * 32 + quad * 8);
            float4 v1 = *(const float4*)(rp + ks * 32 + quad * 8 + 4);
            bf16x8 a;
            a[0] = (short)f2bf(v0.x); a[1] = (short)f2bf(v0.y);
            a[2] = (short)f2bf(v0.z); a[3] = (short)f2bf(v0.w);
            a[4] = (short)f2bf(v1.x); a[5] = (short)f2bf(v1.y);
            a[6] = (short)f2bf(v1.z); a[7] = (short)f2bf(v1.w);
            afr[rt][ks] = a;
        }
    }

    #pragma unroll
    for (int p = 0; p < 2; ++p) {              // ct-parity pass; d = p*16 + l15
        const int d = p * 16 + l15;

        f32x4 acc[2][4];
        #pragma unroll
        for (int rt = 0; rt < 2; ++rt)
            #pragma unroll
            for (int c = 0; c < 4; ++c)
                acc[rt][c] = (f32x4){0.f, 0.f, 0.f, 0.f};

        #pragma unroll
        for (int ks = 0; ks < 2; ++ks) {
            #pragma unroll
            for (int c = 0; c < 4; ++c) {
                bf16x8 b = *(const bf16x8*)&WeTg[((2 * c + p) * 16 + l15) * 64 + ks * 32 + quad * 8];
                acc[0][c] = __builtin_amdgcn_mfma_f32_16x16x32_bf16(afr[0][ks], b, acc[0][c], 0, 0, 0);
                acc[1][c] = __builtin_amdgcn_mfma_f32_16x16x32_bf16(afr[1][ks], b, acc[1][c], 0, 0, 0);
            }
        }

        // epilogue: out_d = sum_h w_h * (E_h + V_h); COALESCED write
        #pragma unroll
        for (int idx = 0; idx < 8; ++idx) {
            int rt = idx >> 2, r = idx & 3;
            int el = base + rt * 16 + quad * 4 + r;
            unsigned d0 = p ? vpg[idx].z : vpg[idx].x;   // h0,h1
            unsigned d1 = p ? vpg[idx].w : vpg[idx].y;   // h2,h3
            float out = w8[idx][0] * (acc[rt][0][r] + bflo(d0))
                      + w8[idx][1] * (acc[rt][1][r] + bfhi(d0))
                      + w8[idx][2] * (acc[rt][2][r] + bflo(d1))
                      + w8[idx][3] * (acc[rt][3][r] + bfhi(d1));
            msg[(size_t)el * OUT_DIM + d] = f2bf(out);
        }
    }
}

// --- K6: per-node aggregate; msg gathered via sorted (64B full lines,
// coalesced across the 32-lane group), 2-way unrolled so two lines are in
// flight. base path precomputed in node_qkv.
__global__ __launch_bounds__(256) void aggregate5(
    const u16* __restrict__ msg, const float* __restrict__ baseout,
    const int* __restrict__ sorted, const int* __restrict__ startp,
    float* __restrict__ out)
{
    int id = blockIdx.x * 256 + threadIdx.x;   // N*32 threads exactly
    int n = id >> 5, d = id & 31;
    float acc = baseout[id];
    int s = startp[n], e = startp[n + 1];
    int i = s;
    for (; i + 1 < e; i += 2) {
        int e0 = sorted[i], e1 = sorted[i + 1];
        float m0 = bf2f(msg[(size_t)e0 * OUT_DIM + d]);
        float m1 = bf2f(msg[(size_t)e1 * OUT_DIM + d]);
        acc += m0 + m1;
    }
    if (i < e)
        acc += bf2f(msg[(size_t)sorted[i] * OUT_DIM + d]);
    out[id] = fmaxf(acc, 0.f);
}

// ---------------------------------------------------------------- launcher
extern "C" void kernel_launch(void* const* d_in, const int* in_sizes, int n_in,
                              void* d_out, int out_size, void* d_ws, size_t ws_size,
                              hipStream_t stream) {
    const float* nodes     = (const float*)d_in[0];
    const float* edges     = (const float*)d_in[1];
    const int*   senders   = (const int*)d_in[2];
    const int*   receivers = (const int*)d_in[3];
    const float* Wq = (const float*)d_in[4];
    const float* bq = (const float*)d_in[5];
    const float* Wk = (const float*)d_in[6];
    const float* bk = (const float*)d_in[7];
    const float* Wv = (const float*)d_in[8];
    const float* bv = (const float*)d_in[9];
    const float* We = (const float*)d_in[10];
    const float* Wu = (const float*)d_in[11];
    const float* bu = (const float*)d_in[12];
    float* out = (float*)d_out;

    // ---- workspace layout (all chunks 16B-aligned)
    char* p = (char*)d_ws;
    u16* Qb    = (u16*)p; p += (size_t)N_NODES * HID * 2;          // 12.8 MB
    u16* Kb    = (u16*)p; p += (size_t)N_NODES * HID * 2;          // 12.8 MB
    u16* Vperm = (u16*)p; p += (size_t)N_NODES * HID * 2;          // 12.8 MB
    u16* WT_all= (u16*)p; p += (size_t)(3 * HID * HID + OUT_DIM * HID) * 2;  // 104 KB
    u16* WeTg  = (u16*)p; p += (size_t)HID * D_EDGE * 2;           // 16 KB
    float* wspill = (float*)p; p += (size_t)N_EDGES * 4 * 4;       // 12.8 MB (rare path)
    float* wnorm  = (float*)p; p += (size_t)N_EDGES * 4 * 4;       // 12.8 MB
    u16* msg   = (u16*)p; p += (size_t)N_EDGES * OUT_DIM * 2;      // 51.2 MB
    float* baseout = (float*)p; p += (size_t)N_NODES * OUT_DIM * 4;// 6.4 MB
    int* count  = (int*)p; p += (size_t)N_NODES * 4;
    int* incl   = (int*)p; p += (size_t)N_NODES * 4;
    int* startp = (int*)p; p += (size_t)(N_NODES + 4) * 4;
    int* cursor = (int*)p; p += (size_t)N_NODES * 4;
    int* sorted = (int*)p; p += (size_t)N_EDGES * 4;
    int* ssend  = (int*)p; p += (size_t)N_EDGES * 4;
    int* bsum   = (int*)p; p += 256 * 4;
    int* boff   = (int*)p; p += 256 * 4;

    const int SCAN_BLOCKS = (N_NODES + 255) / 256;   // 196

    hipLaunchKernelGGL(zero_i32, dim3(SCAN_BLOCKS), dim3(256), 0, stream, count, N_NODES);
    hipLaunchKernelGGL(hist_kernel, dim3(N_EDGES / 256), dim3(256), 0, stream,
                       receivers, count);
    hipLaunchKernelGGL(scan1, dim3(SCAN_BLOCKS), dim3(256), 0, stream, count, incl, bsum);
    hipLaunchKernelGGL(scan2, dim3(1), dim3(256), 0, stream, bsum, boff, SCAN_BLOCKS);
    hipLaunchKernelGGL(scan3, dim3(SCAN_BLOCKS), dim3(256), 0, stream,
                       incl, count, boff, startp, cursor);
    hipLaunchKernelGGL(scatter_v5, dim3(N_EDGES / 256), dim3(256), 0, stream,
                       senders, receivers, cursor, sorted, ssend);
    hipLaunchKernelGGL(prep_weights, dim3(61440 / 256), dim3(256), 0, stream,
                       Wq, Wk, Wv, We, Wu, WT_all, WeTg);
    hipLaunchKernelGGL(node_qkv_v4, dim3((N_NODES + 127) / 128), dim3(256), 0, stream,
                       nodes, WT_all, bq, bk, bv, bu, Qb, Kb, Vperm, baseout);
    hipLaunchKernelGGL(node_softmax, dim3(N_NODES / 4), dim3(256), 0, stream,
                       Qb, Kb, startp, sorted, ssend, wspill, wnorm);
    hipLaunchKernelGGL(edge_messages_v11, dim3(N_EDGES / 128), dim3(256), 0, stream,
                       edges, WeTg, Vperm, wnorm, senders, msg);
    hipLaunchKernelGGL(aggregate5, dim3(N_NODES * OUT_DIM / 256), dim3(256), 0, stream,
                       msg, baseout, sorted, startp, out);
}